// Round 3
// baseline (252.247 us; speedup 1.0000x reference)
//
#include <hip/hip_runtime.h>
#include <math.h>

namespace {

constexpr int LNUM = 2097152;        // L
constexpr int NROW = 5;              // N
constexpr int NSER = 10;             // rows total (0..4 rppg, 5..9 ppg)
constexpr int TPB = 256;
constexpr int EPL = 16;              // elements per lane (one 64B line)
constexpr int CHUNK = TPB * EPL;     // 4096 per block
constexpr int CPR = LNUM / CHUNK;    // 512 chunks per row
constexpr int NBLK = NSER * CPR;     // 5120
constexpr int MAXC = 688;            // max candidates/chunk (peaks >=6 apart -> <=683)

struct Agg { int first; int last; int c; double s; };

__device__ __forceinline__ Agg combine(const Agg& a, const Agg& b) {
  // ordered segment-concat monoid: a LEFT, b RIGHT (non-commutative)
  Agg r;
  r.first = (a.first >= 0) ? a.first : b.first;
  r.last  = (b.last >= 0) ? b.last : a.last;
  r.s = a.s + b.s;
  r.c = a.c + b.c;
  if (a.last >= 0 && b.first >= 0) {
    r.s += 1.0 / (double)(b.first - a.last);
    r.c += 1;
  }
  return r;
}

// Per-lane: 16 contiguous elements at row-relative offset s (s % 16 == 0).
// Own data = one 64B line via 4x dwordx4; halo +-5 via shuffles from
// neighbor lanes; lanes 0/63 patch halo with guarded global loads (-inf pad
// at row edges). Window-11 max via register doubling (m2/m4/m8).
// X[i] = x[s-5+i]  (i=0..25);  w[t] = max over window centered at X[5+t].
// NOTE: no __launch_bounds__ occupancy cap anywhere — round-2 showed a
// 48-VGPR clamp forces ~45 MB of scratch spills in this routine.
__device__ __forceinline__ void window16(const float* __restrict__ x, int s,
                                         float X[26], float w[16]) {
  const float4* q = reinterpret_cast<const float4*>(x + s);
  float4 f0 = q[0], f1 = q[1], f2 = q[2], f3 = q[3];
  X[5] = f0.x;  X[6] = f0.y;  X[7] = f0.z;  X[8] = f0.w;
  X[9] = f1.x;  X[10] = f1.y; X[11] = f1.z; X[12] = f1.w;
  X[13] = f2.x; X[14] = f2.y; X[15] = f2.z; X[16] = f2.w;
  X[17] = f3.x; X[18] = f3.y; X[19] = f3.z; X[20] = f3.w;
#pragma unroll
  for (int j = 0; j < 5; ++j) X[j] = __shfl_up(X[16 + j], 1);      // x[s-5+j]
#pragma unroll
  for (int j = 0; j < 5; ++j) X[21 + j] = __shfl_down(X[5 + j], 1); // x[s+16+j]
  const int lane = threadIdx.x & 63;
  if (lane == 0) {
#pragma unroll
    for (int j = 0; j < 5; ++j) {
      int g = s - 5 + j;
      X[j] = (g >= 0) ? x[g] : -INFINITY;
    }
  }
  if (lane == 63) {
#pragma unroll
    for (int j = 0; j < 5; ++j) {
      int g = s + 16 + j;
      X[21 + j] = (g < LNUM) ? x[g] : -INFINITY;
    }
  }
  float m2[25];
#pragma unroll
  for (int i = 0; i < 25; ++i) m2[i] = fmaxf(X[i], X[i + 1]);
  float m4[23];
#pragma unroll
  for (int i = 0; i < 23; ++i) m4[i] = fmaxf(m2[i], m2[i + 2]);
  float m8[19];
#pragma unroll
  for (int i = 0; i < 19; ++i) m8[i] = fmaxf(m4[i], m4[i + 4]);
#pragma unroll
  for (int t = 0; t < 16; ++t) w[t] = fmaxf(m8[t], m8[t + 3]);  // X[t..t+10]
}

__device__ __forceinline__ const float* row_ptr(const float* rppg,
                                                const float* ppg, int rw) {
  return (rw < NROW) ? rppg + (size_t)rw * LNUM
                     : ppg + (size_t)(rw - NROW) * LNUM;
}

// Pass 1 (single full-data read): per-chunk {sum, peak-value-sum, peak-count}
// AND materialized candidate-peak list (pos, val-bits) in position order.
// Candidate order = threadIdx order x t order = position order, via
// block-wide exclusive scan of per-lane candidate counts. NO atomics.
// Block 0 also zeroes the ticket counter for pass 2 (kernel-boundary
// coherence guarantees visibility to the next kernel in the stream).
__global__ void stats_collect_kernel(
    const float* __restrict__ rppg, const float* __restrict__ ppg,
    double* __restrict__ psum, double* __restrict__ ppk,
    int* __restrict__ pnpk, int* __restrict__ ccnt,
    int2* __restrict__ cand, int* __restrict__ done) {
  const int bid = blockIdx.x;
  const int rw = bid >> 9;          // /CPR
  const int chunk = bid & (CPR - 1);
  const float* x = row_ptr(rppg, ppg, rw);
  const int lane = threadIdx.x & 63;
  const int wid = threadIdx.x >> 6;
  const int s = chunk * CHUNK + wid * (64 * EPL) + lane * EPL;

  if (bid == 0 && threadIdx.x == 0) *done = 0;

  float X[26], w[16];
  window16(x, s, X, w);

  double tsum = 0.0, tpk = 0.0;
  int tn = 0;
#pragma unroll
  for (int t = 0; t < 16; ++t) {
    float v = X[5 + t];
    tsum += (double)v;
    if (v == w[t]) { tpk += (double)v; ++tn; }
  }
  const int cnt = tn;  // per-lane candidate count (survives the reduce below)

  // stats reduce
#pragma unroll
  for (int off = 32; off > 0; off >>= 1) {
    tsum += __shfl_down(tsum, off);
    tpk  += __shfl_down(tpk, off);
    tn   += __shfl_down(tn, off);
  }

  // wave-level inclusive scan of cnt for candidate offsets
  int inc = cnt;
#pragma unroll
  for (int off = 1; off < 64; off <<= 1) {
    int u = __shfl_up(inc, off);
    if (lane >= off) inc += u;
  }

  __shared__ double wsum[4], wpk[4];
  __shared__ int wn[4], wtot[4];
  if (lane == 0) { wsum[wid] = tsum; wpk[wid] = tpk; wn[wid] = tn; }
  if (lane == 63) wtot[wid] = inc;
  __syncthreads();

  int wpre = 0;
#pragma unroll
  for (int i = 0; i < 4; ++i) if (i < wid) wpre += wtot[i];
  int off0 = wpre + inc - cnt;  // block-exclusive offset, position-ordered
  const int total = wtot[0] + wtot[1] + wtot[2] + wtot[3];

  int2* cb = cand + (size_t)bid * MAXC;
  int o = off0;
#pragma unroll
  for (int t = 0; t < 16; ++t) {
    float v = X[5 + t];
    if (v == w[t] && o < MAXC) {
      int2 e; e.x = s + t; e.y = __float_as_int(v);
      cb[o] = e;
      ++o;
    }
  }

  if (threadIdx.x == 0) {
    psum[bid] = wsum[0] + wsum[1] + wsum[2] + wsum[3];
    ppk[bid]  = wpk[0] + wpk[1] + wpk[2] + wpk[3];
    pnpk[bid] = wn[0] + wn[1] + wn[2] + wn[3];
    ccnt[bid] = (total < MAXC) ? total : MAXC;
  }
}

// Pass 2 (single-pass finish): per-chunk ordered gap aggregates FROM THE
// CANDIDATE LIST only (no raw-data re-read). Per-row threshold re-derived
// per block from the 512 chunk partials (10 KB/row, L2-resident). Each
// block publishes its Agg via agent-scope atomic stores, takes a ticket;
// the LAST block reads all 5120 Aggs back (agent-scope atomic loads — safe
// across XCD L2s) and computes the per-row HRs and the final score.
// x_norm > mean_pk_norm/2  <=>  x > (mu + mean_pk_raw)/2  (affine, sd cancels)
__global__ void gap_final_kernel(
    const double* __restrict__ psum, const double* __restrict__ ppk,
    const int* __restrict__ pnpk, const int* __restrict__ ccnt,
    const int2* __restrict__ cand,
    int* __restrict__ cfirst, int* __restrict__ clast,
    double* __restrict__ csum, int* __restrict__ cnum,
    int* __restrict__ done, const int* __restrict__ fsp,
    float* __restrict__ out) {
  const int bid = blockIdx.x;
  const int rw = bid >> 9;
  const int t = threadIdx.x;
  const int lane = t & 63;
  const int wid = t >> 6;

  __shared__ double ws_[4], wp_[4];
  __shared__ int wn_[4];
  __shared__ double sthr;
  __shared__ Agg waggs[4];
  __shared__ int islast;
  __shared__ double shr[NSER];

  // inline per-row threshold from chunk partials
  double s0 = psum[rw * CPR + t] + psum[rw * CPR + t + 256];
  double p0 = ppk[rw * CPR + t] + ppk[rw * CPR + t + 256];
  int n0 = pnpk[rw * CPR + t] + pnpk[rw * CPR + t + 256];
#pragma unroll
  for (int off = 32; off > 0; off >>= 1) {
    s0 += __shfl_down(s0, off);
    p0 += __shfl_down(p0, off);
    n0 += __shfl_down(n0, off);
  }
  if (lane == 0) { ws_[wid] = s0; wp_[wid] = p0; wn_[wid] = n0; }
  __syncthreads();
  if (t == 0) {
    double S = ws_[0] + ws_[1] + ws_[2] + ws_[3];
    double P = wp_[0] + wp_[1] + wp_[2] + wp_[3];
    double Nn = (double)(wn_[0] + wn_[1] + wn_[2] + wn_[3]);
    sthr = 0.5 * (S / (double)LNUM + P / Nn);
  }
  __syncthreads();
  const float th = (float)sthr;

  // candidates: thread t owns the (ordered) triple {3t, 3t+1, 3t+2}
  const int cnt = ccnt[bid];
  const int2* cb = cand + (size_t)bid * MAXC;

  Agg a; a.first = -1; a.last = -1; a.c = 0; a.s = 0.0;
#pragma unroll
  for (int j = 0; j < 3; ++j) {
    int idx = 3 * t + j;
    if (idx < cnt) {
      int2 e = cb[idx];
      float v = __int_as_float(e.y);
      if (v > th) {
        int p = e.x;
        if (a.last >= 0) { a.s += 1.0 / (double)(p - a.last); ++a.c; }
        else a.first = p;
        a.last = p;
      }
    }
  }
  // ordered wave tree: lane i's segment is immediately left of lane i+off's
#pragma unroll
  for (int off = 1; off < 64; off <<= 1) {
    Agg b;
    b.first = __shfl_down(a.first, off);
    b.last  = __shfl_down(a.last, off);
    b.c     = __shfl_down(a.c, off);
    b.s     = __shfl_down(a.s, off);
    a = combine(a, b);
  }
  if (lane == 0) waggs[wid] = a;
  __syncthreads();

  // publish + ticket (thread 0)
  if (t == 0) {
    Agg r = waggs[0];
    r = combine(r, waggs[1]);
    r = combine(r, waggs[2]);
    r = combine(r, waggs[3]);
    __hip_atomic_store(&cfirst[bid], r.first, __ATOMIC_RELAXED,
                       __HIP_MEMORY_SCOPE_AGENT);
    __hip_atomic_store(&clast[bid], r.last, __ATOMIC_RELAXED,
                       __HIP_MEMORY_SCOPE_AGENT);
    __hip_atomic_store(&csum[bid], r.s, __ATOMIC_RELAXED,
                       __HIP_MEMORY_SCOPE_AGENT);
    __hip_atomic_store(&cnum[bid], r.c, __ATOMIC_RELAXED,
                       __HIP_MEMORY_SCOPE_AGENT);
    int prev = __hip_atomic_fetch_add(done, 1, __ATOMIC_ACQ_REL,
                                      __HIP_MEMORY_SCOPE_AGENT);
    islast = (prev == NBLK - 1) ? 1 : 0;
  }
  __syncthreads();
  if (!islast) return;

  // ---- last block: final reduction (thread t covers chunks {2t, 2t+1}) ----
  for (int r = 0; r < NSER; ++r) {
    const int i0 = r * CPR + 2 * t;
    Agg a0, a1;
    a0.first = __hip_atomic_load(&cfirst[i0], __ATOMIC_RELAXED,
                                 __HIP_MEMORY_SCOPE_AGENT);
    a0.last  = __hip_atomic_load(&clast[i0], __ATOMIC_RELAXED,
                                 __HIP_MEMORY_SCOPE_AGENT);
    a0.c     = __hip_atomic_load(&cnum[i0], __ATOMIC_RELAXED,
                                 __HIP_MEMORY_SCOPE_AGENT);
    a0.s     = __hip_atomic_load(&csum[i0], __ATOMIC_RELAXED,
                                 __HIP_MEMORY_SCOPE_AGENT);
    a1.first = __hip_atomic_load(&cfirst[i0 + 1], __ATOMIC_RELAXED,
                                 __HIP_MEMORY_SCOPE_AGENT);
    a1.last  = __hip_atomic_load(&clast[i0 + 1], __ATOMIC_RELAXED,
                                 __HIP_MEMORY_SCOPE_AGENT);
    a1.c     = __hip_atomic_load(&cnum[i0 + 1], __ATOMIC_RELAXED,
                                 __HIP_MEMORY_SCOPE_AGENT);
    a1.s     = __hip_atomic_load(&csum[i0 + 1], __ATOMIC_RELAXED,
                                 __HIP_MEMORY_SCOPE_AGENT);
    a0 = combine(a0, a1);
#pragma unroll
    for (int off = 1; off < 64; off <<= 1) {
      Agg b;
      b.first = __shfl_down(a0.first, off);
      b.last  = __shfl_down(a0.last, off);
      b.c     = __shfl_down(a0.c, off);
      b.s     = __shfl_down(a0.s, off);
      a0 = combine(a0, b);
    }
    if (lane == 0) waggs[wid] = a0;
    __syncthreads();
    if (t == 0) {
      Agg rr = waggs[0];
      rr = combine(rr, waggs[1]);
      rr = combine(rr, waggs[2]);
      rr = combine(rr, waggs[3]);
      shr[r] = 60.0 * (double)fsp[0] * rr.s / (double)rr.c;
    }
    __syncthreads();
  }
  if (t == 0) {
    double acc = 0.0;
    for (int r = 0; r < NROW; ++r)
      acc += fabs(shr[NROW + r] - shr[r]) / shr[NROW + r];
    out[0] = (float)(acc / (double)NROW);
  }
}

}  // namespace

extern "C" void kernel_launch(void* const* d_in, const int* in_sizes, int n_in,
                              void* d_out, int out_size, void* d_ws, size_t ws_size,
                              hipStream_t stream) {
  const float* rppg = (const float*)d_in[0];
  const float* ppg  = (const float*)d_in[1];
  const int* fsp    = (const int*)d_in[2];
  float* out        = (float*)d_out;
  char* ws          = (char*)d_ws;

  // ws layout (all 8-aligned)
  double* psum   = (double*)(ws);            // 5120*8  = 40960
  double* ppk    = (double*)(ws + 40960);    // 40960   -> 81920
  int*    pnpk   = (int*)(ws + 81920);       // 20480   -> 102400
  int*    ccnt   = (int*)(ws + 102400);      // 20480   -> 122880
  double* csum   = (double*)(ws + 122880);   // 40960   -> 163840
  int*    cfirst = (int*)(ws + 163840);      // 20480   -> 184320
  int*    clast  = (int*)(ws + 184320);      // 20480   -> 204800
  int*    cnum   = (int*)(ws + 204800);      // 20480   -> 225280
  int*    done   = (int*)(ws + 225280);      // 64      -> 225344
  int2*   cand   = (int2*)(ws + 225344);     // 5120*688*8 = 28180480 -> ~28.4 MB

  stats_collect_kernel<<<NBLK, TPB, 0, stream>>>(rppg, ppg, psum, ppk, pnpk,
                                                 ccnt, cand, done);
  gap_final_kernel<<<NBLK, TPB, 0, stream>>>(psum, ppk, pnpk, ccnt, cand,
                                             cfirst, clast, csum, cnum,
                                             done, fsp, out);
  (void)in_sizes; (void)n_in; (void)out_size; (void)ws_size;
}

// Round 4
// 147.673 us; speedup vs baseline: 1.7081x; 1.7081x over previous
//
#include <hip/hip_runtime.h>
#include <math.h>

namespace {

constexpr int LNUM = 2097152;        // L
constexpr int NROW = 5;              // N
constexpr int NSER = 10;             // rows total (0..4 rppg, 5..9 ppg)
constexpr int TPB = 256;
constexpr int EPL = 16;              // elements per lane (one 64B line)
constexpr int CHUNK = TPB * EPL;     // 4096 per block
constexpr int CPR = LNUM / CHUNK;    // 512 chunks per row
constexpr int NBLK = NSER * CPR;     // 5120
constexpr int MAXC = 688;            // max candidates/chunk (peaks >=6 apart -> <=683)

struct Agg { int first; int last; int c; double s; };

__device__ __forceinline__ Agg combine(const Agg& a, const Agg& b) {
  // ordered segment-concat monoid: a LEFT, b RIGHT (non-commutative)
  Agg r;
  r.first = (a.first >= 0) ? a.first : b.first;
  r.last  = (b.last >= 0) ? b.last : a.last;
  r.s = a.s + b.s;
  r.c = a.c + b.c;
  if (a.last >= 0 && b.first >= 0) {
    r.s += 1.0 / (double)(b.first - a.last);
    r.c += 1;
  }
  return r;
}

// Per-lane: 16 contiguous elements at row-relative offset s (s % 16 == 0).
// Own data = one 64B line via 4x dwordx4; halo +-5 via shuffles from
// neighbor lanes; lanes 0/63 patch halo with guarded global loads (-inf pad
// at row edges). Window-11 max via register doubling (m2/m4/m8).
// X[i] = x[s-5+i]  (i=0..25);  w[t] = max over window centered at X[5+t].
// NOTE: no __launch_bounds__ occupancy cap anywhere — round-2 showed a
// 48-VGPR clamp forces ~45 MB of scratch spills in this routine.
__device__ __forceinline__ void window16(const float* __restrict__ x, int s,
                                         float X[26], float w[16]) {
  const float4* q = reinterpret_cast<const float4*>(x + s);
  float4 f0 = q[0], f1 = q[1], f2 = q[2], f3 = q[3];
  X[5] = f0.x;  X[6] = f0.y;  X[7] = f0.z;  X[8] = f0.w;
  X[9] = f1.x;  X[10] = f1.y; X[11] = f1.z; X[12] = f1.w;
  X[13] = f2.x; X[14] = f2.y; X[15] = f2.z; X[16] = f2.w;
  X[17] = f3.x; X[18] = f3.y; X[19] = f3.z; X[20] = f3.w;
#pragma unroll
  for (int j = 0; j < 5; ++j) X[j] = __shfl_up(X[16 + j], 1);      // x[s-5+j]
#pragma unroll
  for (int j = 0; j < 5; ++j) X[21 + j] = __shfl_down(X[5 + j], 1); // x[s+16+j]
  const int lane = threadIdx.x & 63;
  if (lane == 0) {
#pragma unroll
    for (int j = 0; j < 5; ++j) {
      int g = s - 5 + j;
      X[j] = (g >= 0) ? x[g] : -INFINITY;
    }
  }
  if (lane == 63) {
#pragma unroll
    for (int j = 0; j < 5; ++j) {
      int g = s + 16 + j;
      X[21 + j] = (g < LNUM) ? x[g] : -INFINITY;
    }
  }
  float m2[25];
#pragma unroll
  for (int i = 0; i < 25; ++i) m2[i] = fmaxf(X[i], X[i + 1]);
  float m4[23];
#pragma unroll
  for (int i = 0; i < 23; ++i) m4[i] = fmaxf(m2[i], m2[i + 2]);
  float m8[19];
#pragma unroll
  for (int i = 0; i < 19; ++i) m8[i] = fmaxf(m4[i], m4[i + 4]);
#pragma unroll
  for (int t = 0; t < 16; ++t) w[t] = fmaxf(m8[t], m8[t + 3]);  // X[t..t+10]
}

__device__ __forceinline__ const float* row_ptr(const float* rppg,
                                                const float* ppg, int rw) {
  return (rw < NROW) ? rppg + (size_t)rw * LNUM
                     : ppg + (size_t)(rw - NROW) * LNUM;
}

// Pass 1 (single full-data read): per-chunk {sum, peak-value-sum, peak-count}
// AND materialized candidate-peak list (pos, val-bits) in position order.
// Candidate order = threadIdx order x t order = position order, via
// block-wide exclusive scan of per-lane candidate counts. NO atomics.
__global__ void stats_collect_kernel(
    const float* __restrict__ rppg, const float* __restrict__ ppg,
    double* __restrict__ psum, double* __restrict__ ppk,
    int* __restrict__ pnpk, int* __restrict__ ccnt,
    int2* __restrict__ cand) {
  const int bid = blockIdx.x;
  const int rw = bid >> 9;          // /CPR
  const int chunk = bid & (CPR - 1);
  const float* x = row_ptr(rppg, ppg, rw);
  const int lane = threadIdx.x & 63;
  const int wid = threadIdx.x >> 6;
  const int s = chunk * CHUNK + wid * (64 * EPL) + lane * EPL;

  float X[26], w[16];
  window16(x, s, X, w);

  double tsum = 0.0, tpk = 0.0;
  int tn = 0;
#pragma unroll
  for (int t = 0; t < 16; ++t) {
    float v = X[5 + t];
    tsum += (double)v;
    if (v == w[t]) { tpk += (double)v; ++tn; }
  }
  const int cnt = tn;  // per-lane candidate count (survives the reduce below)

  // stats reduce
#pragma unroll
  for (int off = 32; off > 0; off >>= 1) {
    tsum += __shfl_down(tsum, off);
    tpk  += __shfl_down(tpk, off);
    tn   += __shfl_down(tn, off);
  }

  // wave-level inclusive scan of cnt for candidate offsets
  int inc = cnt;
#pragma unroll
  for (int off = 1; off < 64; off <<= 1) {
    int u = __shfl_up(inc, off);
    if (lane >= off) inc += u;
  }

  __shared__ double wsum[4], wpk[4];
  __shared__ int wn[4], wtot[4];
  if (lane == 0) { wsum[wid] = tsum; wpk[wid] = tpk; wn[wid] = tn; }
  if (lane == 63) wtot[wid] = inc;
  __syncthreads();

  int wpre = 0;
#pragma unroll
  for (int i = 0; i < 4; ++i) if (i < wid) wpre += wtot[i];
  int off0 = wpre + inc - cnt;  // block-exclusive offset, position-ordered
  const int total = wtot[0] + wtot[1] + wtot[2] + wtot[3];

  int2* cb = cand + (size_t)bid * MAXC;
  int o = off0;
#pragma unroll
  for (int t = 0; t < 16; ++t) {
    float v = X[5 + t];
    if (v == w[t] && o < MAXC) {
      int2 e; e.x = s + t; e.y = __float_as_int(v);
      cb[o] = e;
      ++o;
    }
  }

  if (threadIdx.x == 0) {
    psum[bid] = wsum[0] + wsum[1] + wsum[2] + wsum[3];
    ppk[bid]  = wpk[0] + wpk[1] + wpk[2] + wpk[3];
    pnpk[bid] = wn[0] + wn[1] + wn[2] + wn[3];
    ccnt[bid] = (total < MAXC) ? total : MAXC;
  }
}

// Pass 2: per-chunk ordered gap aggregates FROM THE CANDIDATE LIST only
// (no raw-data re-read). Per-row threshold re-derived per block from the
// 512 chunk partials (10 KB/row, L2-resident). NO atomics (round-3 lesson:
// per-block agent-scope fences cost an L2 writeback each — O(grid) fences
// turned a 4 us kernel into 137 us).
// x_norm > mean_pk_norm/2  <=>  x > (mu + mean_pk_raw)/2  (affine, sd cancels)
__global__ void gap_kernel(
    const double* __restrict__ psum, const double* __restrict__ ppk,
    const int* __restrict__ pnpk, const int* __restrict__ ccnt,
    const int2* __restrict__ cand,
    int* __restrict__ cfirst, int* __restrict__ clast,
    double* __restrict__ csum, int* __restrict__ cnum) {
  const int bid = blockIdx.x;
  const int rw = bid >> 9;
  const int t = threadIdx.x;
  const int lane = t & 63;
  const int wid = t >> 6;

  // inline per-row threshold from chunk partials
  double s0 = psum[rw * CPR + t] + psum[rw * CPR + t + 256];
  double p0 = ppk[rw * CPR + t] + ppk[rw * CPR + t + 256];
  int n0 = pnpk[rw * CPR + t] + pnpk[rw * CPR + t + 256];
#pragma unroll
  for (int off = 32; off > 0; off >>= 1) {
    s0 += __shfl_down(s0, off);
    p0 += __shfl_down(p0, off);
    n0 += __shfl_down(n0, off);
  }
  __shared__ double ws_[4], wp_[4];
  __shared__ int wn_[4];
  __shared__ double sthr;
  if (lane == 0) { ws_[wid] = s0; wp_[wid] = p0; wn_[wid] = n0; }
  __syncthreads();
  if (t == 0) {
    double S = ws_[0] + ws_[1] + ws_[2] + ws_[3];
    double P = wp_[0] + wp_[1] + wp_[2] + wp_[3];
    double Nn = (double)(wn_[0] + wn_[1] + wn_[2] + wn_[3]);
    sthr = 0.5 * (S / (double)LNUM + P / Nn);
  }
  __syncthreads();
  const float th = (float)sthr;

  // candidates: thread t owns the (ordered) triple {3t, 3t+1, 3t+2}
  const int cnt = ccnt[bid];
  const int2* cb = cand + (size_t)bid * MAXC;

  Agg a; a.first = -1; a.last = -1; a.c = 0; a.s = 0.0;
#pragma unroll
  for (int j = 0; j < 3; ++j) {
    int idx = 3 * t + j;
    if (idx < cnt) {
      int2 e = cb[idx];
      float v = __int_as_float(e.y);
      if (v > th) {
        int p = e.x;
        if (a.last >= 0) { a.s += 1.0 / (double)(p - a.last); ++a.c; }
        else a.first = p;
        a.last = p;
      }
    }
  }
  // ordered wave tree: lane i's segment is immediately left of lane i+off's
#pragma unroll
  for (int off = 1; off < 64; off <<= 1) {
    Agg b;
    b.first = __shfl_down(a.first, off);
    b.last  = __shfl_down(a.last, off);
    b.c     = __shfl_down(a.c, off);
    b.s     = __shfl_down(a.s, off);
    a = combine(a, b);
  }

  __shared__ Agg waggs[4];
  if (lane == 0) waggs[wid] = a;
  __syncthreads();
  if (t == 0) {
    Agg r = waggs[0];
    r = combine(r, waggs[1]);
    r = combine(r, waggs[2]);
    r = combine(r, waggs[3]);
    cfirst[bid] = r.first; clast[bid] = r.last;
    csum[bid] = r.s; cnum[bid] = r.c;
  }
}

// Final: one block; rows parallel across waves (wave w owns rows w, w+4,
// w+8 -> max 3 sequential rows instead of 10). Within a wave, lane l
// combines chunks [8l, 8l+8) in order (more load ILP), then a 6-stage
// ordered shuffle tree. No atomics, no cross-block traffic.
__global__ void final_kernel(
    const int* __restrict__ cfirst, const int* __restrict__ clast,
    const double* __restrict__ csum, const int* __restrict__ cnum,
    const int* __restrict__ fsp, float* __restrict__ out) {
  __shared__ double shr[NSER];
  const int t = threadIdx.x;
  const int lane = t & 63;
  const int wid = t >> 6;

  for (int r = wid; r < NSER; r += 4) {
    const int base = r * CPR + lane * 8;
    Agg a; a.first = -1; a.last = -1; a.c = 0; a.s = 0.0;
#pragma unroll
    for (int j = 0; j < 8; ++j) {
      Agg b;
      b.first = cfirst[base + j];
      b.last  = clast[base + j];
      b.c     = cnum[base + j];
      b.s     = csum[base + j];
      a = combine(a, b);   // identity-left on first iter; stays ordered
    }
    // ordered wave tree: lane i covers chunks [8i,8i+8), adjacent to i+off
#pragma unroll
    for (int off = 1; off < 64; off <<= 1) {
      Agg b;
      b.first = __shfl_down(a.first, off);
      b.last  = __shfl_down(a.last, off);
      b.c     = __shfl_down(a.c, off);
      b.s     = __shfl_down(a.s, off);
      a = combine(a, b);
    }
    if (lane == 0) shr[r] = 60.0 * (double)fsp[0] * a.s / (double)a.c;
  }
  __syncthreads();
  if (t == 0) {
    double acc = 0.0;
    for (int r = 0; r < NROW; ++r)
      acc += fabs(shr[NROW + r] - shr[r]) / shr[NROW + r];
    out[0] = (float)(acc / (double)NROW);
  }
}

}  // namespace

extern "C" void kernel_launch(void* const* d_in, const int* in_sizes, int n_in,
                              void* d_out, int out_size, void* d_ws, size_t ws_size,
                              hipStream_t stream) {
  const float* rppg = (const float*)d_in[0];
  const float* ppg  = (const float*)d_in[1];
  const int* fsp    = (const int*)d_in[2];
  float* out        = (float*)d_out;
  char* ws          = (char*)d_ws;

  // ws layout (all 8-aligned)
  double* psum   = (double*)(ws);            // 5120*8  = 40960
  double* ppk    = (double*)(ws + 40960);    // 40960   -> 81920
  int*    pnpk   = (int*)(ws + 81920);       // 20480   -> 102400
  int*    ccnt   = (int*)(ws + 102400);      // 20480   -> 122880
  double* csum   = (double*)(ws + 122880);   // 40960   -> 163840
  int*    cfirst = (int*)(ws + 163840);      // 20480   -> 184320
  int*    clast  = (int*)(ws + 184320);      // 20480   -> 204800
  int*    cnum   = (int*)(ws + 204800);      // 20480   -> 225280
  int2*   cand   = (int2*)(ws + 225280);     // 5120*688*8 = 28180480 -> ~28.4 MB

  stats_collect_kernel<<<NBLK, TPB, 0, stream>>>(rppg, ppg, psum, ppk, pnpk,
                                                 ccnt, cand);
  gap_kernel<<<NBLK, TPB, 0, stream>>>(psum, ppk, pnpk, ccnt, cand,
                                       cfirst, clast, csum, cnum);
  final_kernel<<<1, TPB, 0, stream>>>(cfirst, clast, csum, cnum, fsp, out);
  (void)in_sizes; (void)n_in; (void)out_size; (void)ws_size;
}